// Round 1
// baseline (6314.303 us; speedup 1.0000x reference)
//
#include <hip/hip_runtime.h>

// Decoder: B=256, T=128, ENC=256, DEC=256, OUT=3. All fp32.
//
// Design (round 1, correctness + counter anchor):
//  - One persistent workgroup per batch element (256 WGs x 512 threads).
//    Recurrence (h,c) is per-b independent -> no grid sync, no per-step launches.
//  - z2 = x @ attn2_w.T precomputed once, staged fp32 in LDS per WG (128x257 pad).
//  - Folds: W_comb = w_ih @ tilde_w (1024x260 padded, transposed),
//           W_head = fc2_w @ fc1_w (3x512) -> head computed in-loop, no th buffer.
//  - All streamed weights stored TRANSPOSED so lane tid reads column tid
//    (coalesced dword loads; avoids L1 thrash of per-thread-row streaming).
// Predicted bound: per-CU L2 BW on weight streams (~2.76 MB/step/CU) ~2.3-2.7 ms.

#define TT 128
#define ENCD 256

__device__ __forceinline__ float fast_tanh(float x) {
  float e = __expf(2.f * x);
  return 1.f - 2.f / (e + 1.f);
}
__device__ __forceinline__ float fast_sig(float x) {
  return 1.f / (1.f + __expf(-x));
}

// ---------------- precompute kernels ----------------

// generic transpose: dst[c*R + r] = src[r*C + c]
__global__ void k_transpose(const float* __restrict__ src, float* __restrict__ dst,
                            int R, int C) {
  int idx = blockIdx.x * 256 + threadIdx.x;
  if (idx >= R * C) return;
  int r = idx / C, c = idx - r * C;
  dst[(size_t)c * R + r] = src[idx];
}

// z2[row][f] = sum_e x[row][e] * a2w[f][e] + a2b[f]; rows = b*128+t (32768 rows)
// reads a2wT (transposed attn2_w) for coalescing.
__global__ __launch_bounds__(256) void k_z2(const float* __restrict__ x,
                                            const float* __restrict__ a2wT,
                                            const float* __restrict__ a2b,
                                            float* __restrict__ z2) {
  __shared__ float xt[16][257];
  const int r0 = blockIdx.x * 16;
  const int tid = threadIdx.x;
  for (int idx = tid; idx < 16 * 256; idx += 256) {
    int rr = idx >> 8, e = idx & 255;
    xt[rr][e] = x[(size_t)(r0 + rr) * 256 + e];
  }
  __syncthreads();
  const int f = tid;
  float bias = a2b[f];
  float acc[16];
#pragma unroll
  for (int rr = 0; rr < 16; ++rr) acc[rr] = bias;
  for (int e = 0; e < 256; ++e) {
    float w = a2wT[(size_t)e * 256 + f];  // coalesced across f
#pragma unroll
    for (int rr = 0; rr < 16; ++rr) acc[rr] += w * xt[rr][e];
  }
#pragma unroll
  for (int rr = 0; rr < 16; ++rr) z2[(size_t)(r0 + rr) * 256 + f] = acc[rr];
}

// wcombT[k][n] = sum_j w_ih[n][j] * tilde_w[j][k]   (k<259; row 259 zero-pad)
// bcomb[n] = sum_j w_ih[n][j]*tilde_b[j] + b_ih[n] + b_hh[n]
__global__ __launch_bounds__(320) void k_wcomb(const float* __restrict__ w_ih,
                                               const float* __restrict__ tilde_w,
                                               const float* __restrict__ tilde_b,
                                               const float* __restrict__ b_ih,
                                               const float* __restrict__ b_hh,
                                               float* __restrict__ wcombT,
                                               float* __restrict__ bcomb) {
  __shared__ float wrow[512];
  __shared__ float bred[320];
  const int n = blockIdx.x;
  const int tid = threadIdx.x;
  for (int j = tid; j < 512; j += 320) wrow[j] = w_ih[(size_t)n * 512 + j];
  __syncthreads();
  if (tid < 259) {
    float acc = 0.f;
    for (int j = 0; j < 512; ++j) acc += wrow[j] * tilde_w[(size_t)j * 259 + tid];
    wcombT[(size_t)tid * 1024 + n] = acc;
  } else if (tid == 259) {
    wcombT[(size_t)259 * 1024 + n] = 0.f;
  }
  float p = 0.f;
  for (int j = tid; j < 512; j += 320) p += wrow[j] * tilde_b[j];
  bred[tid] = p;
  __syncthreads();
  if (tid == 0) {
    float s = 0.f;
    for (int j = 0; j < 320; ++j) s += bred[j];
    bcomb[n] = s + b_ih[n] + b_hh[n];
  }
}

// whead[o][k] = sum_j fc2_w[o][j] * fc1_w[j][k]; bhead[o] = fc2_w[o]·fc1_b + fc2_b[o]
__global__ __launch_bounds__(512) void k_whead(const float* __restrict__ fc1_w,
                                               const float* __restrict__ fc1_b,
                                               const float* __restrict__ fc2_w,
                                               const float* __restrict__ fc2_b,
                                               float* __restrict__ whead,
                                               float* __restrict__ bhead) {
  const int k = threadIdx.x;
#pragma unroll
  for (int o = 0; o < 3; ++o) {
    float acc = 0.f;
    for (int j = 0; j < 256; ++j) acc += fc2_w[o * 256 + j] * fc1_w[(size_t)j * 512 + k];
    whead[o * 512 + k] = acc;
  }
  if (k < 3) {
    float acc = fc2_b[k];
    for (int j = 0; j < 256; ++j) acc += fc2_w[k * 256 + j] * fc1_b[j];
    bhead[k] = acc;
  }
}

// ---------------- main persistent decoder ----------------

__global__ __launch_bounds__(512) void k_decoder(
    const float* __restrict__ xg,     // input_encoded [256][128][256]
    const float* __restrict__ yg,     // y_seq [256][128][3]
    const float* __restrict__ a1wT,   // [512][256] transposed attn1_w
    const float* __restrict__ a1b,    // [256]
    const float* __restrict__ a3w,    // [256]
    const float* __restrict__ whhT,   // [256][1024] transposed w_hh
    const float* __restrict__ z2g,    // [32768][256]
    const float* __restrict__ wcombT, // [260][1024]
    const float* __restrict__ bcomb,  // [1024]
    const float* __restrict__ whead,  // [3][512]
    const float* __restrict__ bhead,  // [3]
    float* __restrict__ outg)         // [256][128][3]
{
  __shared__ float z2s[128][257];
  __shared__ float hbuf[256], cbuf[256];
  __shared__ float zpart[512], scpart[512], cpart[512];
  __shared__ float gbuf[1024];
  __shared__ float ctxs[256];
  __shared__ float attv[128];
  __shared__ float w3s[256];
  __shared__ float ubuf[260];
  __shared__ float sred[8];

  const int b = blockIdx.x;
  const int tid = threadIdx.x;

  // stage z2[b] into LDS (fp32), init h/c/w3
  for (int idx = tid; idx < 128 * 256; idx += 512) {
    int r = idx >> 8, f = idx & 255;
    z2s[r][f] = z2g[((size_t)(b * TT + r) << 8) + f];
  }
  if (tid < 256) { w3s[tid] = a3w[tid]; hbuf[tid] = 0.f; cbuf[tid] = 0.f; }
  __syncthreads();

  const int f_z = tid & 255;
  const int kh = tid >> 8;                 // 0: k<256 (h half), 1: k>=256 (c half)
  const float a1bias = (kh == 0) ? a1b[f_z] : 0.f;
  const float* a1p = a1wT + (size_t)(kh * 256) * 256 + f_z;  // stride 256 per k
  const float* wh0 = whhT + tid;            // stride 1024 per k
  const float* wh1 = whhT + 512 + tid;
  const float* wc0 = wcombT + tid;
  const float* wc1 = wcombT + 512 + tid;
  const float bc0 = bcomb[tid], bc1 = bcomb[tid + 512];

  for (int t = 0; t < TT; ++t) {
    float yreg = (tid < 3) ? yg[(size_t)(b * TT + t) * 3 + tid] : 0.f;

    // ---- Phase Z: z1 partial (k-split over halves) + gates_h (n=tid, tid+512)
    float gh0, gh1;
    {
      const float* hcp = kh ? cbuf : hbuf;
      float za = 0.f, zb = 0.f, g0a = 0.f, g0b = 0.f, g1a = 0.f, g1b = 0.f;
#pragma unroll 4
      for (int k = 0; k < 256; k += 2) {
        float hk0 = hbuf[k], hk1 = hbuf[k + 1];
        float hc0 = hcp[k], hc1 = hcp[k + 1];
        za += a1p[(size_t)k * 256] * hc0;
        zb += a1p[(size_t)(k + 1) * 256] * hc1;
        g0a += wh0[(size_t)k * 1024] * hk0;
        g0b += wh0[(size_t)(k + 1) * 1024] * hk1;
        g1a += wh1[(size_t)k * 1024] * hk0;
        g1b += wh1[(size_t)(k + 1) * 1024] * hk1;
      }
      zpart[tid] = za + zb + a1bias;
      gh0 = g0a + g0b;
      gh1 = g1a + g1b;
    }
    __syncthreads();  // S1

    // ---- Phase S: scores, t'=tid&127, f-quarter q=tid>>7
    {
      int tp = tid & 127, q = tid >> 7;
      const float* zrow = &z2s[tp][0];
      float acc = 0.f;
      int f0 = q * 64;
#pragma unroll 4
      for (int f = f0; f < f0 + 64; ++f) {
        float z1f = zpart[f] + zpart[f + 256];
        acc += fast_tanh(z1f + zrow[f]) * w3s[f];
      }
      scpart[tid] = acc;
    }
    __syncthreads();  // S2
    float sc_reg = 0.f;
    if (tid < 128) {
      sc_reg = scpart[tid] + scpart[tid + 128] + scpart[tid + 256] + scpart[tid + 384];
      float m = sc_reg;
#pragma unroll
      for (int off = 32; off > 0; off >>= 1) m = fmaxf(m, __shfl_xor(m, off));
      if ((tid & 63) == 0) sred[tid >> 6] = m;
    }
    __syncthreads();  // S3
    if (tid < 128) {
      float m = fmaxf(sred[0], sred[1]);
      float e = __expf(sc_reg - m);
      attv[tid] = e;
      float s = e;
#pragma unroll
      for (int off = 32; off > 0; off >>= 1) s += __shfl_xor(s, off);
      if ((tid & 63) == 0) sred[2 + (tid >> 6)] = s;
    }
    __syncthreads();  // S4
    const float rsum = 1.f / (sred[2] + sred[3]);

    // ---- Phase C: context, e=tid&255, t'-half th=tid>>8
    {
      int e = tid & 255, th = tid >> 8;
      const float* xcol = xg + ((size_t)(b * TT + th * 64) << 8) + e;
      float acc = 0.f;
#pragma unroll 8
      for (int tp = 0; tp < 64; ++tp) acc += attv[th * 64 + tp] * xcol[(size_t)tp << 8];
      cpart[tid] = acc;
    }
    __syncthreads();  // S5a
    if (tid < 256) {
      float cv = (cpart[tid] + cpart[tid + 256]) * rsum;
      ctxs[tid] = cv;
      ubuf[3 + tid] = cv;
    }
    if (tid < 3) ubuf[tid] = yreg;
    if (tid == 3) ubuf[259] = 0.f;
    __syncthreads();  // S5b

    // ---- Phase G: gates = W_comb·u + gates_h + b_comb  (n=tid, tid+512)
    {
      float a0 = 0.f, a1 = 0.f, b0 = 0.f, b1 = 0.f;
#pragma unroll 4
      for (int k = 0; k < 260; k += 2) {
        float u0 = ubuf[k], u1 = ubuf[k + 1];
        a0 += wc0[(size_t)k * 1024] * u0;
        a1 += wc0[(size_t)(k + 1) * 1024] * u1;
        b0 += wc1[(size_t)k * 1024] * u0;
        b1 += wc1[(size_t)(k + 1) * 1024] * u1;
      }
      gbuf[tid] = a0 + a1 + gh0 + bc0;
      gbuf[tid + 512] = b0 + b1 + gh1 + bc1;
    }
    __syncthreads();  // S6
    if (tid < 256) {
      float gi = gbuf[tid], gf = gbuf[tid + 256], gg = gbuf[tid + 512], go = gbuf[tid + 768];
      float cn = fast_sig(gf) * cbuf[tid] + fast_sig(gi) * fast_tanh(gg);
      float hn = fast_sig(go) * fast_tanh(cn);
      if (t < TT - 1) {  // reference skips state update on last step
        hbuf[tid] = hn;
        cbuf[tid] = cn;
      }
    }
    __syncthreads();  // S7

    // ---- Phase H: out[b,t,o] = W_head[o]·[h2, ctx] + b_head[o]
    if (tid < 192) {
      int o = tid >> 6, lane = tid & 63;
      float acc = 0.f;
#pragma unroll
      for (int q2 = 0; q2 < 8; ++q2) {
        int k = lane + (q2 << 6);
        float v = (k < 256) ? hbuf[k] : ctxs[k - 256];
        acc += whead[o * 512 + k] * v;
      }
#pragma unroll
      for (int off = 32; off > 0; off >>= 1) acc += __shfl_xor(acc, off);
      if (lane == 0) outg[(size_t)(b * TT + t) * 3 + o] = acc + bhead[o];
    }
    // no barrier needed here: next write of hbuf/ctxs is many barriers away
  }
}

// ---------------- launch ----------------

extern "C" void kernel_launch(void* const* d_in, const int* in_sizes, int n_in,
                              void* d_out, int out_size, void* d_ws, size_t ws_size,
                              hipStream_t stream) {
  const float* x   = (const float*)d_in[0];
  const float* y   = (const float*)d_in[1];
  const float* a1w = (const float*)d_in[2];
  const float* a1b = (const float*)d_in[3];
  const float* a2w = (const float*)d_in[4];
  const float* a2b = (const float*)d_in[5];
  const float* a3w = (const float*)d_in[6];
  // d_in[7] = attn3_b: constant added to all scores -> softmax-invariant, skipped
  const float* tw  = (const float*)d_in[8];
  const float* tb  = (const float*)d_in[9];
  const float* wih = (const float*)d_in[10];
  const float* whh = (const float*)d_in[11];
  const float* bih = (const float*)d_in[12];
  const float* bhh = (const float*)d_in[13];
  const float* f1w = (const float*)d_in[14];
  const float* f1b = (const float*)d_in[15];
  const float* f2w = (const float*)d_in[16];
  const float* f2b = (const float*)d_in[17];
  float* out = (float*)d_out;

  float* ws = (float*)d_ws;
  float* z2     = ws;                         // 32768*256  = 8,388,608
  float* a1wT   = z2 + (size_t)32768 * 256;   // 512*256    =   131,072
  float* whhT   = a1wT + 512 * 256;           // 256*1024   =   262,144
  float* a2wT   = whhT + 256 * 1024;          // 256*256    =    65,536
  float* wcombT = a2wT + 256 * 256;           // 260*1024   =   266,240
  float* bcomb  = wcombT + 260 * 1024;        // 1024
  float* whead  = bcomb + 1024;               // 3*512
  float* bhead  = whead + 3 * 512;            // 3
  // total ~36.5 MB of workspace

  // transposes (src R x C -> dst C x R)
  k_transpose<<<dim3((256 * 512 + 255) / 256), dim3(256), 0, stream>>>(a1w, a1wT, 256, 512);
  k_transpose<<<dim3((1024 * 256 + 255) / 256), dim3(256), 0, stream>>>(whh, whhT, 1024, 256);
  k_transpose<<<dim3((256 * 256 + 255) / 256), dim3(256), 0, stream>>>(a2w, a2wT, 256, 256);

  k_z2<<<dim3(2048), dim3(256), 0, stream>>>(x, a2wT, a2b, z2);
  k_wcomb<<<dim3(1024), dim3(320), 0, stream>>>(wih, tw, tb, bih, bhh, wcombT, bcomb);
  k_whead<<<dim3(1), dim3(512), 0, stream>>>(f1w, f1b, f2w, f2b, whead, bhead);

  k_decoder<<<dim3(256), dim3(512), 0, stream>>>(x, y, a1wT, a1b, a3w, whhT, z2,
                                                 wcombT, bcomb, whead, bhead, out);
}

// Round 2
// 2981.623 us; speedup vs baseline: 2.1177x; 2.1177x over previous
//
#include <hip/hip_runtime.h>

// Decoder: B=256, T=128, ENC=256, DEC=256, OUT=3. All fp32 in/out.
//
// Round 2: kill the HBM-bound x re-read (round-1 counter: hbm_bytes 3.5 GB
// = dur 6.3 ms at 557 GB/s).
//  - z2[b] AND x[b] staged in LDS as fp16 (66 KB each, rows padded to 258
//    halves -> conflict-free ds reads). Main loop global traffic = weights only.
//  - Streamed weights (a1, whh, wcomb) packed fp16 half2-along-k, consumed
//    via v_dot2_f32_f16 (fp32 accumulate): halves L2 bytes AND VALU ops.
//  - 1024-thread persistent WG per batch element (16 waves/CU latency hiding).
//  - Softmax without max-subtraction: |score| <= sum|w3| ~ 25 << 88, safe.

#define TT 128

typedef _Float16 h2v __attribute__((ext_vector_type(2)));

__device__ __forceinline__ float fdot2(h2v a, h2v b, float c) {
#if __has_builtin(__builtin_amdgcn_fdot2)
  return __builtin_amdgcn_fdot2(a, b, c, false);
#else
  return c + (float)a[0] * (float)b[0] + (float)a[1] * (float)b[1];
#endif
}

__device__ __forceinline__ float fast_tanh(float x) {
  float e = __expf(2.f * x);
  return 1.f - 2.f / (e + 1.f);
}
__device__ __forceinline__ float fast_sig(float x) {
  return 1.f / (1.f + __expf(-x));
}

// ---------------- precompute kernels ----------------

// fp32 transpose (for attn2_w only): dst[c*R + r] = src[r*C + c]
__global__ void k_transpose(const float* __restrict__ src, float* __restrict__ dst,
                            int R, int C) {
  int idx = blockIdx.x * 256 + threadIdx.x;
  if (idx >= R * C) return;
  int r = idx / C, c = idx - r * C;
  dst[(size_t)c * R + r] = src[idx];
}

// x -> fp16 pairs
__global__ void k_xhalf(const float2* __restrict__ x2, h2v* __restrict__ xh2, int n2) {
  int i = blockIdx.x * 256 + threadIdx.x;
  if (i >= n2) return;
  float2 v = x2[i];
  h2v o = {(_Float16)v.x, (_Float16)v.y};
  xh2[i] = o;
}

// a1h2[k2][f] = (attn1_w[f][2k2], attn1_w[f][2k2+1]); k2<256, f<256
__global__ void k_pack_a1(const float* __restrict__ a1w, h2v* __restrict__ a1h2) {
  int idx = blockIdx.x * 256 + threadIdx.x;  // 65536
  int k2 = idx >> 8, f = idx & 255;
  h2v o = {(_Float16)a1w[(size_t)f * 512 + 2 * k2],
           (_Float16)a1w[(size_t)f * 512 + 2 * k2 + 1]};
  a1h2[(size_t)k2 * 256 + f] = o;
}

// whh2[k2][n] = (w_hh[n][2k2], w_hh[n][2k2+1]); k2<128, n<1024
__global__ void k_pack_whh(const float* __restrict__ whh, h2v* __restrict__ whh2) {
  int idx = blockIdx.x * 256 + threadIdx.x;  // 131072
  int k2 = idx >> 10, n = idx & 1023;
  h2v o = {(_Float16)whh[(size_t)n * 256 + 2 * k2],
           (_Float16)whh[(size_t)n * 256 + 2 * k2 + 1]};
  whh2[(size_t)k2 * 1024 + n] = o;
}

// z2'[row][f] = sum_e x[row][e]*attn2_w[f][e] + a2b[f] + a1b[f]  (fp16 out)
__global__ __launch_bounds__(256) void k_z2(const float* __restrict__ x,
                                            const float* __restrict__ a2wT,
                                            const float* __restrict__ a2b,
                                            const float* __restrict__ a1b,
                                            _Float16* __restrict__ z2h) {
  __shared__ float xt[16][257];
  const int r0 = blockIdx.x * 16;
  const int tid = threadIdx.x;
  for (int idx = tid; idx < 16 * 256; idx += 256) {
    int rr = idx >> 8, e = idx & 255;
    xt[rr][e] = x[(size_t)(r0 + rr) * 256 + e];
  }
  __syncthreads();
  const int f = tid;
  float bias = a2b[f] + a1b[f];
  float acc[16];
#pragma unroll
  for (int rr = 0; rr < 16; ++rr) acc[rr] = bias;
  for (int e = 0; e < 256; ++e) {
    float w = a2wT[(size_t)e * 256 + f];
#pragma unroll
    for (int rr = 0; rr < 16; ++rr) acc[rr] += w * xt[rr][e];
  }
#pragma unroll
  for (int rr = 0; rr < 16; ++rr) z2h[(size_t)(r0 + rr) * 256 + f] = (_Float16)acc[rr];
}

// wc2[k2][n] = fp16 pair of (w_ih @ tilde_w)[n][2k2, 2k2+1], k row 259 zero-pad
// bcomb[n] = w_ih[n]·tilde_b + b_ih[n] + b_hh[n]
__global__ __launch_bounds__(256) void k_wcomb(const float* __restrict__ w_ih,
                                               const float* __restrict__ tilde_w,
                                               const float* __restrict__ tilde_b,
                                               const float* __restrict__ b_ih,
                                               const float* __restrict__ b_hh,
                                               h2v* __restrict__ wc2,
                                               float* __restrict__ bcomb) {
  __shared__ float wrow[512];
  __shared__ float bred[256];
  const int n = blockIdx.x;
  const int tid = threadIdx.x;
  for (int j = tid; j < 512; j += 256) wrow[j] = w_ih[(size_t)n * 512 + j];
  __syncthreads();
  if (tid < 130) {
    int k0 = 2 * tid, k1 = 2 * tid + 1;
    float a0 = 0.f, a1 = 0.f;
    for (int j = 0; j < 512; ++j) {
      float w = wrow[j];
      a0 += w * tilde_w[(size_t)j * 259 + k0];
      if (k1 < 259) a1 += w * tilde_w[(size_t)j * 259 + k1];
    }
    h2v o = {(_Float16)a0, (_Float16)a1};
    wc2[(size_t)tid * 1024 + n] = o;
  }
  float p = 0.f;
  for (int j = tid; j < 512; j += 256) p += wrow[j] * tilde_b[j];
  bred[tid] = p;
  __syncthreads();
  if (tid == 0) {
    float s = 0.f;
    for (int j = 0; j < 256; ++j) s += bred[j];
    bcomb[n] = s + b_ih[n] + b_hh[n];
  }
}

// whead[o][k] = fc2_w @ fc1_w; bhead[o] = fc2_w[o]·fc1_b + fc2_b[o]
__global__ __launch_bounds__(512) void k_whead(const float* __restrict__ fc1_w,
                                               const float* __restrict__ fc1_b,
                                               const float* __restrict__ fc2_w,
                                               const float* __restrict__ fc2_b,
                                               float* __restrict__ whead,
                                               float* __restrict__ bhead) {
  const int k = threadIdx.x;
#pragma unroll
  for (int o = 0; o < 3; ++o) {
    float acc = 0.f;
    for (int j = 0; j < 256; ++j) acc += fc2_w[o * 256 + j] * fc1_w[(size_t)j * 512 + k];
    whead[o * 512 + k] = acc;
  }
  if (k < 3) {
    float acc = fc2_b[k];
    for (int j = 0; j < 256; ++j) acc += fc2_w[k * 256 + j] * fc1_b[j];
    bhead[k] = acc;
  }
}

// ---------------- main persistent decoder ----------------

__global__ __launch_bounds__(1024, 4) void k_decoder(
    const _Float16* __restrict__ z2g,  // [32768][256] fp16 (incl a2b+a1b)
    const _Float16* __restrict__ xhg,  // [256][128][256] fp16
    const float* __restrict__ yg,      // y_seq [256][128][3] fp32
    const float* __restrict__ a3w,     // [256]
    const h2v* __restrict__ a1h2,      // [256][256] pairs-along-k
    const h2v* __restrict__ whh2,      // [128][1024]
    const h2v* __restrict__ wc2,       // [130][1024]
    const float* __restrict__ bcomb,   // [1024]
    const float* __restrict__ whead,   // [3][512]
    const float* __restrict__ bhead,   // [3]
    float* __restrict__ outg)          // [256][128][3]
{
  __shared__ __align__(16) _Float16 z2s[128][258];  // 66,048 B
  __shared__ __align__(16) _Float16 xs[128][258];   // 66,048 B
  __shared__ float zpart[1024];
  __shared__ float scpart[1024];
  __shared__ float cpart[1024];
  __shared__ float gbuf[1024];
  __shared__ float z1c[256];
  __shared__ float hbuf[256], cbuf[256], ctxs[256], w3s[256];
  __shared__ __align__(16) _Float16 hb_h[256], cb_h[256];
  __shared__ __align__(16) _Float16 ub_h[260];
  __shared__ float attv[128];
  __shared__ float sred[8];

  const int b = blockIdx.x;
  const int tid = threadIdx.x;

  // stage z2[b], x[b] into LDS (fp16, padded rows)
  {
    const h2v* zsrc = (const h2v*)(z2g + (size_t)b * TT * 256);
    const h2v* xsrc = (const h2v*)(xhg + (size_t)b * TT * 256);
    for (int i = tid; i < TT * 128; i += 1024) {
      int t = i >> 7, fp = i & 127;
      *(h2v*)&z2s[t][2 * fp] = zsrc[i];
      *(h2v*)&xs[t][2 * fp] = xsrc[i];
    }
  }
  if (tid < 256) {
    w3s[tid] = a3w[tid];
    hbuf[tid] = 0.f; cbuf[tid] = 0.f;
    hb_h[tid] = (_Float16)0.f; cb_h[tid] = (_Float16)0.f;
  }
  __syncthreads();  // B0

  const int f_z = tid & 255;
  const int qz = tid >> 8;  // k-quarter for z1 (0,1: h | 2,3: c)
  const h2v* a1p = a1h2 + (size_t)(qz * 64) * 256 + f_z;
  const h2v* whp = whh2 + tid;
  const h2v* wcp = wc2 + tid;
  const float bc = bcomb[tid];

  for (int t = 0; t < TT; ++t) {
    float yreg = (tid < 3) ? yg[(size_t)(b * TT + t) * 3 + tid] : 0.f;

    // ---- Phase Z: z1 partials (k-quarters) + gates_h (n = tid)
    float ghr;
    {
      const h2v* hc2 = (qz < 2) ? (const h2v*)hb_h : (const h2v*)cb_h;
      const int jb = (qz & 1) * 64;
      float za = 0.f, zb = 0.f;
#pragma unroll 4
      for (int j2 = 0; j2 < 64; j2 += 2) {
        za = fdot2(a1p[(size_t)j2 * 256], hc2[jb + j2], za);
        zb = fdot2(a1p[(size_t)(j2 + 1) * 256], hc2[jb + j2 + 1], zb);
      }
      zpart[tid] = za + zb;
      const h2v* h2 = (const h2v*)hb_h;
      float g0 = 0.f, g1 = 0.f;
#pragma unroll 4
      for (int k2 = 0; k2 < 128; k2 += 2) {
        g0 = fdot2(whp[(size_t)k2 * 1024], h2[k2], g0);
        g1 = fdot2(whp[(size_t)(k2 + 1) * 1024], h2[k2 + 1], g1);
      }
      ghr = g0 + g1;
    }
    __syncthreads();  // B1

    // ---- combine z1
    if (tid < 256)
      z1c[tid] = zpart[tid] + zpart[tid + 256] + zpart[tid + 512] + zpart[tid + 768];
    __syncthreads();  // B2

    // ---- Phase S: scores; tp = tid&127, q = tid>>7 (8 groups x 32 f)
    {
      int tp = tid & 127, q = tid >> 7;
      int f0 = q * 32;
      const h2v* zp = (const h2v*)&z2s[tp][f0];
      float acc = 0.f;
#pragma unroll
      for (int i = 0; i < 16; ++i) {
        h2v zz = zp[i];
        int f = f0 + 2 * i;
        acc += fast_tanh(z1c[f] + (float)zz[0]) * w3s[f];
        acc += fast_tanh(z1c[f + 1] + (float)zz[1]) * w3s[f + 1];
      }
      scpart[tid] = acc;
    }
    __syncthreads();  // B3

    // ---- softmax (no max-sub: |score| <= sum|w3| ~ 25 << 88)
    if (tid < 128) {
      float sc = scpart[tid] + scpart[tid + 128] + scpart[tid + 256] + scpart[tid + 384] +
                 scpart[tid + 512] + scpart[tid + 640] + scpart[tid + 768] + scpart[tid + 896];
      float e = __expf(sc);
      attv[tid] = e;
      float s = e;
#pragma unroll
      for (int off = 32; off > 0; off >>= 1) s += __shfl_xor(s, off);
      if ((tid & 63) == 0) sred[2 + (tid >> 6)] = s;
    }
    __syncthreads();  // B4

    // ---- Phase C: context partials; e = tid&255, th = tid>>8 (4 x 32 t)
    {
      int e = tid & 255, th = tid >> 8;
      float acc = 0.f;
#pragma unroll 8
      for (int tp = 0; tp < 32; ++tp) {
        int tt = th * 32 + tp;
        acc += attv[tt] * (float)xs[tt][e];
      }
      cpart[tid] = acc;
    }
    __syncthreads();  // B5

    const float rsum = 1.f / (sred[2] + sred[3]);
    if (tid < 256) {
      float cv = (cpart[tid] + cpart[tid + 256] + cpart[tid + 512] + cpart[tid + 768]) * rsum;
      ctxs[tid] = cv;
      ub_h[3 + tid] = (_Float16)cv;
    }
    if (tid < 3) ub_h[tid] = (_Float16)yreg;
    if (tid == 3) ub_h[259] = (_Float16)0.f;
    __syncthreads();  // B6

    // ---- Phase G: gates = W_comb·u + gates_h + b_comb (n = tid)
    {
      const h2v* u2 = (const h2v*)ub_h;
      float a0 = 0.f, a1 = 0.f;
#pragma unroll 2
      for (int k2 = 0; k2 < 130; k2 += 2) {
        a0 = fdot2(wcp[(size_t)k2 * 1024], u2[k2], a0);
        if (k2 + 1 < 130) a1 = fdot2(wcp[(size_t)(k2 + 1) * 1024], u2[k2 + 1], a1);
      }
      gbuf[tid] = a0 + a1 + ghr + bc;
    }
    __syncthreads();  // B7

    // ---- LSTM pointwise
    if (tid < 256) {
      float gi = gbuf[tid], gf = gbuf[tid + 256], gg = gbuf[tid + 512], go = gbuf[tid + 768];
      float cn = fast_sig(gf) * cbuf[tid] + fast_sig(gi) * fast_tanh(gg);
      float hn = fast_sig(go) * fast_tanh(cn);
      if (t < TT - 1) {  // reference skips state update on last step
        hbuf[tid] = hn; cbuf[tid] = cn;
        hb_h[tid] = (_Float16)hn; cb_h[tid] = (_Float16)cn;
      }
    }
    __syncthreads();  // B8

    // ---- Phase H: out[b,t,o] = W_head[o]·[h2, ctx] + b_head[o]
    if (tid < 192) {
      int o = tid >> 6, lane = tid & 63;
      float acc = 0.f;
#pragma unroll
      for (int q2 = 0; q2 < 8; ++q2) {
        int k = lane + (q2 << 6);
        float v = (k < 256) ? hbuf[k] : ctxs[k - 256];
        acc += whead[o * 512 + k] * v;
      }
#pragma unroll
      for (int off = 32; off > 0; off >>= 1) acc += __shfl_xor(acc, off);
      if (lane == 0) outg[(size_t)(b * TT + t) * 3 + o] = acc + bhead[o];
    }
    // no barrier: next phase writes only zpart (disjoint from hbuf/ctxs/whead)
  }
}

// ---------------- launch ----------------

extern "C" void kernel_launch(void* const* d_in, const int* in_sizes, int n_in,
                              void* d_out, int out_size, void* d_ws, size_t ws_size,
                              hipStream_t stream) {
  const float* x   = (const float*)d_in[0];
  const float* y   = (const float*)d_in[1];
  const float* a1w = (const float*)d_in[2];
  const float* a1b = (const float*)d_in[3];
  const float* a2w = (const float*)d_in[4];
  const float* a2b = (const float*)d_in[5];
  const float* a3w = (const float*)d_in[6];
  // d_in[7] = attn3_b: softmax-invariant constant, skipped
  const float* tw  = (const float*)d_in[8];
  const float* tb  = (const float*)d_in[9];
  const float* wih = (const float*)d_in[10];
  const float* whh = (const float*)d_in[11];
  const float* bih = (const float*)d_in[12];
  const float* bhh = (const float*)d_in[13];
  const float* f1w = (const float*)d_in[14];
  const float* f1b = (const float*)d_in[15];
  const float* f2w = (const float*)d_in[16];
  const float* f2b = (const float*)d_in[17];
  float* out = (float*)d_out;

  float* ws = (float*)d_ws;
  _Float16* z2h = (_Float16*)ws;                    // 8,388,608 halves (4,194,304 f)
  _Float16* xh  = (_Float16*)(ws + 4194304);        // 8,388,608 halves
  float* a2wT   = ws + 8388608;                     // 65,536 f
  h2v* a1h2     = (h2v*)(ws + 8388608 + 65536);     // 65,536 pairs (65,536 f)
  h2v* whh2     = (h2v*)(ws + 8388608 + 131072);    // 131,072 pairs (131,072 f)
  h2v* wc2      = (h2v*)(ws + 8388608 + 262144);    // 133,120 pairs (133,120 f)
  float* bcomb  = ws + 8388608 + 262144 + 133120;   // 1024
  float* whead  = bcomb + 1024;                     // 1536
  float* bhead  = whead + 1536;                     // 3
  // total ~35.1 MB

  k_transpose<<<dim3((256 * 256 + 255) / 256), dim3(256), 0, stream>>>(a2w, a2wT, 256, 256);
  k_xhalf<<<dim3(16384), dim3(256), 0, stream>>>((const float2*)x, (h2v*)xh, 4194304);
  k_pack_a1<<<dim3(256), dim3(256), 0, stream>>>(a1w, a1h2);
  k_pack_whh<<<dim3(512), dim3(256), 0, stream>>>(whh, whh2);
  k_z2<<<dim3(2048), dim3(256), 0, stream>>>(x, a2wT, a2b, a1b, z2h);
  k_wcomb<<<dim3(1024), dim3(256), 0, stream>>>(wih, tw, tb, bih, bhh, wc2, bcomb);
  k_whead<<<dim3(1), dim3(512), 0, stream>>>(f1w, f1b, f2w, f2b, whead, bhead);

  k_decoder<<<dim3(256), dim3(1024), 0, stream>>>(z2h, xh, y, a3w, a1h2, whh2, wc2,
                                                  bcomb, whead, bhead, out);
}

// Round 3
// 1888.928 us; speedup vs baseline: 3.3428x; 1.5785x over previous
//
#include <hip/hip_runtime.h>

// Decoder: B=256, T=128, ENC=256, DEC=256, OUT=3. All fp32 in/out.
//
// Round 3: instruction-efficiency rebuild (round-2 counters: VALUBusy 53% at
// 23.3 us/step = ~12 us VALU issue from 322 scalar strided weight loads +
// 64-bit addr arithmetic per thread per step).
//  - Weights repacked [k/8][col][8] fp16: 16B f16x8 loads, coalesced across
//    cols, imm-offset addressing -> ~81 loads/thread/step, deep vmcnt pipe.
//  - z2 rows padded to 260 halves; x stored TRANSPOSED [e][t] (132-pad):
//    Phase S/C read b64 vectors, banks distinct (<=2-way, free).
//  - a1 weights and z2 pre-scaled by 2*log2(e): tanh = exp2+add+rcp+fma.
//  - Head weights preloaded to registers (no per-step traffic).
// Predicted: ~9-13 us/step -> 1.1-1.65 ms; VALUBusy 30-40%.

#define TT 128
#define SCL 2.885390081777927f  // 2*log2(e)

typedef _Float16 h2v __attribute__((ext_vector_type(2)));
typedef _Float16 f16x4 __attribute__((ext_vector_type(4)));
typedef _Float16 f16x8 __attribute__((ext_vector_type(8)));

__device__ __forceinline__ float fdot2(h2v a, h2v b, float c) {
#if __has_builtin(__builtin_amdgcn_fdot2)
  return __builtin_amdgcn_fdot2(a, b, c, false);
#else
  return c + (float)a[0] * (float)b[0] + (float)a[1] * (float)b[1];
#endif
}

__device__ __forceinline__ float exp2_fast(float x) {
#if __has_builtin(__builtin_amdgcn_exp2f)
  return __builtin_amdgcn_exp2f(x);
#else
  return exp2f(x);
#endif
}
__device__ __forceinline__ float rcp_fast(float x) {
#if __has_builtin(__builtin_amdgcn_rcpf)
  return __builtin_amdgcn_rcpf(x);
#else
  return 1.f / x;
#endif
}

// tanh(v) given s = SCL*v: 1 - 2/(exp2(s)+1). Saturates correctly via rcp(inf)=0.
__device__ __forceinline__ float tanh_scaled(float s) {
  return fmaf(-2.f, rcp_fast(exp2_fast(s) + 1.f), 1.f);
}
__device__ __forceinline__ float fast_sig(float x) {
  return rcp_fast(1.f + __expf(-x));
}
__device__ __forceinline__ float fast_tanh(float x) {
  return tanh_scaled(x * SCL);
}

__device__ __forceinline__ float dot8(f16x8 w, f16x8 h, float acc) {
  h2v w0 = __builtin_shufflevector(w, w, 0, 1), h0 = __builtin_shufflevector(h, h, 0, 1);
  h2v w1 = __builtin_shufflevector(w, w, 2, 3), h1 = __builtin_shufflevector(h, h, 2, 3);
  h2v w2 = __builtin_shufflevector(w, w, 4, 5), h2 = __builtin_shufflevector(h, h, 4, 5);
  h2v w3 = __builtin_shufflevector(w, w, 6, 7), h3 = __builtin_shufflevector(h, h, 6, 7);
  acc = fdot2(w0, h0, acc);
  acc = fdot2(w1, h1, acc);
  acc = fdot2(w2, h2, acc);
  acc = fdot2(w3, h3, acc);
  return acc;
}

// ---------------- precompute kernels ----------------

// fp32 transpose (attn2_w): dst[c*R + r] = src[r*C + c]
__global__ void k_transpose(const float* __restrict__ src, float* __restrict__ dst,
                            int R, int C) {
  int idx = blockIdx.x * 256 + threadIdx.x;
  if (idx >= R * C) return;
  int r = idx / C, c = idx - r * C;
  dst[(size_t)c * R + r] = src[idx];
}

// z2h[row][f] = SCL*(sum_e x[row][e]*attn2_w[f][e] + a2b[f] + a1b[f]) fp16
// also emits xTg[b][e][t] fp16 (transposed x) from the staged tile.
__global__ __launch_bounds__(256) void k_z2x(const float* __restrict__ x,
                                             const float* __restrict__ a2wT,
                                             const float* __restrict__ a2b,
                                             const float* __restrict__ a1b,
                                             _Float16* __restrict__ z2h,
                                             _Float16* __restrict__ xTg) {
  __shared__ float xt[16][257];
  const int r0 = blockIdx.x * 16;
  const int tid = threadIdx.x;
  for (int idx = tid; idx < 16 * 256; idx += 256) {
    int rr = idx >> 8, e = idx & 255;
    xt[rr][e] = x[(size_t)(r0 + rr) * 256 + e];
  }
  __syncthreads();
  const int f = tid;
  float bias = a2b[f] + a1b[f];
  float acc[16];
#pragma unroll
  for (int rr = 0; rr < 16; ++rr) acc[rr] = bias;
  for (int e = 0; e < 256; ++e) {
    float w = a2wT[(size_t)e * 256 + f];
#pragma unroll
    for (int rr = 0; rr < 16; ++rr) acc[rr] += w * xt[rr][e];
  }
#pragma unroll
  for (int rr = 0; rr < 16; ++rr)
    z2h[(size_t)(r0 + rr) * 256 + f] = (_Float16)(acc[rr] * SCL);
  // transpose emit: b = r0/128, t0 = r0%128; thread owns column e=f
  const int b = r0 >> 7, t0 = r0 & 127;
#pragma unroll
  for (int rr = 0; rr < 16; ++rr)
    xTg[((size_t)b * 256 + f) * 128 + t0 + rr] = (_Float16)xt[rr][f];
}

// a1p8[kc][f][8] = attn1_w[f][kc*8+j] * SCL   (kc<64, f<256)
__global__ void k_pack_a1(const float* __restrict__ a1w, _Float16* __restrict__ dst) {
  int idx = blockIdx.x * 256 + threadIdx.x;  // 131072
  int j = idx & 7, f = (idx >> 3) & 255, kc = idx >> 11;
  dst[idx] = (_Float16)(a1w[(size_t)f * 512 + kc * 8 + j] * SCL);
}

// whh8[kc][n][8] = w_hh[n][kc*8+j]   (kc<32, n<1024)
__global__ void k_pack_whh(const float* __restrict__ whh, _Float16* __restrict__ dst) {
  int idx = blockIdx.x * 256 + threadIdx.x;  // 262144
  int j = idx & 7, n = (idx >> 3) & 1023, kc = idx >> 13;
  dst[idx] = (_Float16)whh[(size_t)n * 256 + kc * 8 + j];
}

// wc8[kc][n][8] fp16 of (w_ih @ tilde_w)[n][kc*8+j], k>=259 zero-padded (kc<33)
// bcomb[n] = w_ih[n]·tilde_b + b_ih[n] + b_hh[n]
__global__ __launch_bounds__(320) void k_wcomb(const float* __restrict__ w_ih,
                                               const float* __restrict__ tilde_w,
                                               const float* __restrict__ tilde_b,
                                               const float* __restrict__ b_ih,
                                               const float* __restrict__ b_hh,
                                               _Float16* __restrict__ wc8,
                                               float* __restrict__ bcomb) {
  __shared__ float wrow[512];
  __shared__ float bred[320];
  const int n = blockIdx.x;
  const int tid = threadIdx.x;
  for (int j = tid; j < 512; j += 320) wrow[j] = w_ih[(size_t)n * 512 + j];
  __syncthreads();
  if (tid < 264) {
    float acc = 0.f;
    if (tid < 259)
      for (int j = 0; j < 512; ++j) acc += wrow[j] * tilde_w[(size_t)j * 259 + tid];
    wc8[(size_t)(tid >> 3) * 8192 + n * 8 + (tid & 7)] = (_Float16)acc;
  }
  float p = 0.f;
  for (int j = tid; j < 512; j += 320) p += wrow[j] * tilde_b[j];
  bred[tid] = p;
  __syncthreads();
  if (tid == 0) {
    float s = 0.f;
    for (int j = 0; j < 320; ++j) s += bred[j];
    bcomb[n] = s + b_ih[n] + b_hh[n];
  }
}

// whead[o][k] = fc2_w @ fc1_w; bhead[o] = fc2_w[o]·fc1_b + fc2_b[o]
__global__ __launch_bounds__(512) void k_whead(const float* __restrict__ fc1_w,
                                               const float* __restrict__ fc1_b,
                                               const float* __restrict__ fc2_w,
                                               const float* __restrict__ fc2_b,
                                               float* __restrict__ whead,
                                               float* __restrict__ bhead) {
  const int k = threadIdx.x;
#pragma unroll
  for (int o = 0; o < 3; ++o) {
    float acc = 0.f;
    for (int j = 0; j < 256; ++j) acc += fc2_w[o * 256 + j] * fc1_w[(size_t)j * 512 + k];
    whead[o * 512 + k] = acc;
  }
  if (k < 3) {
    float acc = fc2_b[k];
    for (int j = 0; j < 256; ++j) acc += fc2_w[k * 256 + j] * fc1_b[j];
    bhead[k] = acc;
  }
}

// ---------------- main persistent decoder ----------------

__global__ __launch_bounds__(1024, 4) void k_decoder(
    const _Float16* __restrict__ z2g,  // [32768][256] fp16, pre-scaled, incl biases
    const _Float16* __restrict__ xTg,  // [256][256 e][128 t] fp16
    const float* __restrict__ yg,      // y_seq [256][128][3] fp32
    const float* __restrict__ a3w,     // [256]
    const _Float16* __restrict__ a1p8, // [64 kc][256 f][8]
    const _Float16* __restrict__ whh8, // [32 kc][1024 n][8]
    const _Float16* __restrict__ wc8,  // [33 kc][1024 n][8]
    const float* __restrict__ bcomb,   // [1024]
    const float* __restrict__ whead,   // [3][512]
    const float* __restrict__ bhead,   // [3]
    float* __restrict__ outg)          // [256][128][3]
{
  __shared__ __align__(16) _Float16 z2s[128][260];  // 66,560 B
  __shared__ __align__(16) _Float16 xs[256][132];   // 67,584 B (transposed x)
  __shared__ float zpart[1024];
  __shared__ float scpart[1024];
  __shared__ float cpart[1024];
  __shared__ float gbuf[1024];
  __shared__ float z1c[256];
  __shared__ float hbuf[256], cbuf[256], ctxs[256], w3s[256];
  __shared__ __align__(16) _Float16 hc8[512];  // [h(256); c(256)]
  __shared__ __align__(16) _Float16 u8[264];   // [y(3); ctx(256); pad0(5)]
  __shared__ float attv[128];
  __shared__ float sred[8];

  const int b = blockIdx.x;
  const int tid = threadIdx.x;

  // stage z2[b] -> [t][260], xT[b] -> [e][132]
  {
    const f16x8* zsrc = (const f16x8*)(z2g + (size_t)b * TT * 256);
    for (int c = tid; c < 4096; c += 1024) {
      int t = c >> 5, fc = c & 31;
      f16x8 v = zsrc[c];
      f16x4 lo = __builtin_shufflevector(v, v, 0, 1, 2, 3);
      f16x4 hi = __builtin_shufflevector(v, v, 4, 5, 6, 7);
      _Float16* d = &z2s[t][fc * 8];
      *(f16x4*)d = lo;
      *(f16x4*)(d + 4) = hi;
    }
    const f16x8* xsrc = (const f16x8*)(xTg + (size_t)b * 256 * 128);
    for (int c = tid; c < 4096; c += 1024) {
      int e = c >> 4, tc = c & 15;
      f16x8 v = xsrc[c];
      f16x4 lo = __builtin_shufflevector(v, v, 0, 1, 2, 3);
      f16x4 hi = __builtin_shufflevector(v, v, 4, 5, 6, 7);
      _Float16* d = &xs[e][tc * 8];
      *(f16x4*)d = lo;
      *(f16x4*)(d + 4) = hi;
    }
  }
  if (tid < 256) {
    w3s[tid] = a3w[tid];
    hbuf[tid] = 0.f; cbuf[tid] = 0.f;
    hc8[tid] = (_Float16)0.f; hc8[256 + tid] = (_Float16)0.f;
  }
  if (tid >= 259 && tid < 264) u8[tid] = (_Float16)0.f;
  __syncthreads();  // B0

  const int f_z = tid & 255;
  const int qz = tid >> 8;  // k-quarter for z1
  const _Float16* pa = a1p8 + ((size_t)(qz * 16) * 256 + f_z) * 8;
  const _Float16* pw = whh8 + (size_t)tid * 8;
  const _Float16* pc = wc8 + (size_t)tid * 8;
  const float bc = bcomb[tid];

  // preload head weights (per-thread fixed)
  float whr[8], bh = 0.f;
  if (tid < 192) {
    int o = tid >> 6, lane = tid & 63;
#pragma unroll
    for (int q2 = 0; q2 < 8; ++q2) whr[q2] = whead[o * 512 + lane + (q2 << 6)];
    bh = bhead[o];
  }

  for (int t = 0; t < TT; ++t) {
    float yreg = (tid < 3) ? yg[(size_t)(b * TT + t) * 3 + tid] : 0.f;

    // ---- Phase Z: z1 partials (4-way k-split) + gates_h (n = tid)
    float ghr;
    {
      float za0 = 0.f, za1 = 0.f;
#pragma unroll 4
      for (int i = 0; i < 16; i += 2) {
        f16x8 w0 = *(const f16x8*)(pa + (size_t)i * 2048);
        f16x8 w1 = *(const f16x8*)(pa + (size_t)(i + 1) * 2048);
        f16x8 h0 = *(const f16x8*)&hc8[(qz * 16 + i) * 8];
        f16x8 h1 = *(const f16x8*)&hc8[(qz * 16 + i + 1) * 8];
        za0 = dot8(w0, h0, za0);
        za1 = dot8(w1, h1, za1);
      }
      zpart[tid] = za0 + za1;
      float g0 = 0.f, g1 = 0.f;
#pragma unroll 4
      for (int kc = 0; kc < 32; kc += 2) {
        f16x8 w0 = *(const f16x8*)(pw + (size_t)kc * 8192);
        f16x8 w1 = *(const f16x8*)(pw + (size_t)(kc + 1) * 8192);
        f16x8 h0 = *(const f16x8*)&hc8[kc * 8];
        f16x8 h1 = *(const f16x8*)&hc8[(kc + 1) * 8];
        g0 = dot8(w0, h0, g0);
        g1 = dot8(w1, h1, g1);
      }
      ghr = g0 + g1;
    }
    __syncthreads();  // B1

    if (tid < 256)
      z1c[tid] = zpart[tid] + zpart[tid + 256] + zpart[tid + 512] + zpart[tid + 768];
    __syncthreads();  // B2

    // ---- Phase S: scores; tp = tid&127, q = tid>>7 (8 groups x 32 f)
    {
      int tp = tid & 127, q = tid >> 7, f0 = q * 32;
      const _Float16* zr = &z2s[tp][f0];
      float acc = 0.f;
#pragma unroll
      for (int i = 0; i < 8; ++i) {
        f16x4 zz = *(const f16x4*)(zr + i * 4);
#pragma unroll
        for (int j = 0; j < 4; ++j) {
          int f = f0 + i * 4 + j;
          acc = fmaf(tanh_scaled(z1c[f] + (float)zz[j]), w3s[f], acc);
        }
      }
      scpart[tid] = acc;
    }
    __syncthreads();  // B3

    // ---- softmax (no max-sub: |score| <= sum|w3| ~ 25 << 88)
    if (tid < 128) {
      float sc = scpart[tid] + scpart[tid + 128] + scpart[tid + 256] + scpart[tid + 384] +
                 scpart[tid + 512] + scpart[tid + 640] + scpart[tid + 768] + scpart[tid + 896];
      float e = __expf(sc);
      attv[tid] = e;
      float s = e;
#pragma unroll
      for (int off = 32; off > 0; off >>= 1) s += __shfl_xor(s, off);
      if ((tid & 63) == 0) sred[2 + (tid >> 6)] = s;
    }
    __syncthreads();  // B4

    // ---- Phase C: context partials; e = tid&255, th4 = tid>>8 (4 x 32 t)
    {
      int e = tid & 255, th4 = tid >> 8;
      const _Float16* xr = &xs[e][th4 * 32];
      float acc = 0.f;
#pragma unroll
      for (int i = 0; i < 8; ++i) {
        f16x4 xv = *(const f16x4*)(xr + i * 4);
#pragma unroll
        for (int j = 0; j < 4; ++j)
          acc = fmaf(attv[th4 * 32 + i * 4 + j], (float)xv[j], acc);
      }
      cpart[tid] = acc;
    }
    __syncthreads();  // B5

    const float rsum = rcp_fast(sred[2] + sred[3]);
    if (tid < 256) {
      float cv = (cpart[tid] + cpart[tid + 256] + cpart[tid + 512] + cpart[tid + 768]) * rsum;
      ctxs[tid] = cv;
      u8[3 + tid] = (_Float16)cv;
    }
    if (tid < 3) u8[tid] = (_Float16)yreg;
    __syncthreads();  // B6

    // ---- Phase G: gates = W_comb·u + gates_h + b_comb (n = tid)
    {
      float a0 = 0.f, a1 = 0.f;
#pragma unroll 4
      for (int kc = 0; kc < 32; kc += 2) {
        f16x8 w0 = *(const f16x8*)(pc + (size_t)kc * 8192);
        f16x8 w1 = *(const f16x8*)(pc + (size_t)(kc + 1) * 8192);
        f16x8 u0 = *(const f16x8*)&u8[kc * 8];
        f16x8 u1 = *(const f16x8*)&u8[(kc + 1) * 8];
        a0 = dot8(w0, u0, a0);
        a1 = dot8(w1, u1, a1);
      }
      a0 = dot8(*(const f16x8*)(pc + (size_t)32 * 8192), *(const f16x8*)&u8[256], a0);
      gbuf[tid] = a0 + a1 + ghr + bc;
    }
    __syncthreads();  // B7

    // ---- LSTM pointwise
    if (tid < 256) {
      float gi = gbuf[tid], gf = gbuf[tid + 256], gg = gbuf[tid + 512], go = gbuf[tid + 768];
      float cn = fast_sig(gf) * cbuf[tid] + fast_sig(gi) * fast_tanh(gg);
      float hn = fast_sig(go) * fast_tanh(cn);
      if (t < TT - 1) {  // reference skips state update on last step
        hbuf[tid] = hn; cbuf[tid] = cn;
        hc8[tid] = (_Float16)hn; hc8[256 + tid] = (_Float16)cn;
      }
    }
    __syncthreads();  // B8

    // ---- Phase H: out[b,t,o] = W_head[o]·[h2, ctx] + b_head[o]
    if (tid < 192) {
      int o = tid >> 6, lane = tid & 63;
      float acc = 0.f;
#pragma unroll
      for (int q2 = 0; q2 < 8; ++q2) {
        int k = lane + (q2 << 6);
        float v = (k < 256) ? hbuf[k] : ctxs[k - 256];
        acc = fmaf(whr[q2], v, acc);
      }
#pragma unroll
      for (int off = 32; off > 0; off >>= 1) acc += __shfl_xor(acc, off);
      if (lane == 0) outg[(size_t)(b * TT + t) * 3 + o] = acc + bh;
    }
    // no barrier: next phase writes only zpart (disjoint from hbuf/ctxs)
  }
}

// ---------------- launch ----------------

extern "C" void kernel_launch(void* const* d_in, const int* in_sizes, int n_in,
                              void* d_out, int out_size, void* d_ws, size_t ws_size,
                              hipStream_t stream) {
  const float* x   = (const float*)d_in[0];
  const float* y   = (const float*)d_in[1];
  const float* a1w = (const float*)d_in[2];
  const float* a1b = (const float*)d_in[3];
  const float* a2w = (const float*)d_in[4];
  const float* a2b = (const float*)d_in[5];
  const float* a3w = (const float*)d_in[6];
  // d_in[7] = attn3_b: softmax-invariant constant, skipped
  const float* tw  = (const float*)d_in[8];
  const float* tb  = (const float*)d_in[9];
  const float* wih = (const float*)d_in[10];
  const float* whh = (const float*)d_in[11];
  const float* bih = (const float*)d_in[12];
  const float* bhh = (const float*)d_in[13];
  const float* f1w = (const float*)d_in[14];
  const float* f1b = (const float*)d_in[15];
  const float* f2w = (const float*)d_in[16];
  const float* f2b = (const float*)d_in[17];
  float* out = (float*)d_out;

  float* ws = (float*)d_ws;
  _Float16* z2h  = (_Float16*)ws;                       // 8,388,608 h = 4,194,304 f
  _Float16* xT   = (_Float16*)(ws + 4194304);           // 8,388,608 h
  float* a2wT    = ws + 8388608;                        // 65,536 f
  _Float16* a1p8 = (_Float16*)(ws + 8388608 + 65536);   // 131,072 h = 65,536 f
  _Float16* whh8 = (_Float16*)(ws + 8388608 + 131072);  // 262,144 h = 131,072 f
  _Float16* wc8  = (_Float16*)(ws + 8388608 + 262144);  // 270,336 h = 135,168 f
  float* bcomb   = ws + 8388608 + 262144 + 135168;      // 1,024
  float* whead   = bcomb + 1024;                        // 1,536
  float* bhead   = whead + 1536;                        // 3
  // total ~35.2 MB

  k_transpose<<<dim3((256 * 256 + 255) / 256), dim3(256), 0, stream>>>(a2w, a2wT, 256, 256);
  k_z2x<<<dim3(2048), dim3(256), 0, stream>>>(x, a2wT, a2b, a1b, z2h, xT);
  k_pack_a1<<<dim3(512), dim3(256), 0, stream>>>(a1w, a1p8);
  k_pack_whh<<<dim3(1024), dim3(256), 0, stream>>>(whh, whh8);
  k_wcomb<<<dim3(1024), dim3(320), 0, stream>>>(wih, tw, tb, bih, bhh, wc8, bcomb);
  k_whead<<<dim3(1), dim3(512), 0, stream>>>(f1w, f1b, f2w, f2b, whead, bhead);

  k_decoder<<<dim3(256), dim3(1024), 0, stream>>>(z2h, xT, y, a3w, a1p8, whh8, wc8,
                                                  bcomb, whead, bhead, out);
}